// Round 7
// baseline (222.790 us; speedup 1.0000x reference)
//
#include <hip/hip_runtime.h>
#include <math.h>

#define H 4
#define NL 5
#define SEQ 610
#define BATCH 128
#define TICKS (SEQ + NL - 1)   // 614 wavefront-pipelined ticks

typedef float v2f __attribute__((ext_vector_type(2)));

#if __has_builtin(__builtin_elementwise_fma)
#define FMA2(a, b, c) __builtin_elementwise_fma((a), (b), (c))
#else
static __device__ __forceinline__ v2f FMA2(v2f a, v2f b, v2f c) {
    v2f r; r[0] = fmaf(a[0], b[0], c[0]); r[1] = fmaf(a[1], b[1], c[1]); return r;
}
#endif

// update_dpp per 32-bit element. CTRL: quad_perm 0x00/0x55/0xAA/0xFF,
// row_shr:4 0x114, row_bcast15 0x142. BC: true -> 0 on invalid, false -> keep old.
template<int CTRL, bool BC>
__device__ __forceinline__ float dpp1(float old_, float src) {
    return __int_as_float(__builtin_amdgcn_update_dpp(
        __float_as_int(old_), __float_as_int(src), CTRL, 0xF, 0xF, BC));
}
template<int CTRL, bool BC>
__device__ __forceinline__ v2f dpp2(v2f old_, v2f src) {
    v2f r;
    r[0] = dpp1<CTRL, BC>(old_[0], src[0]);
    r[1] = dpp1<CTRL, BC>(old_[1], src[1]);
    return r;
}
__device__ __forceinline__ v2f exp22(v2f a) {
    v2f r; r[0] = __builtin_amdgcn_exp2f(a[0]); r[1] = __builtin_amdgcn_exp2f(a[1]); return r;
}
__device__ __forceinline__ v2f rcp2(v2f a) {
    v2f r; r[0] = __builtin_amdgcn_rcpf(a[0]); r[1] = __builtin_amdgcn_rcpf(a[1]); return r;
}

// Lane layout (per 32-lane half): r=lane&31; layers 0-3 = quads 0-3 (r=0..15),
// layer 4 = quad 0 of next DPP row (r=16..19); r>=20 computes junk.
// TWO independent batch streams per wave packed in v2f lanes:
//   stream A = row blockIdx*4 + half, stream B = row blockIdx*4 + 2 + half.
// Gate MACs become v_pk_fma_f32; while one stream stalls on exp2/rcp the other issues.
__global__ __launch_bounds__(64) void lstm_2s_kernel(
    const float* __restrict__ x,      // [128,610,2]
    const float* __restrict__ w_ih0,  // [16,2]
    const float* __restrict__ w_ih,   // [4,16,4]
    const float* __restrict__ w_hh,   // [5,16,4]
    const float* __restrict__ b_ih,   // [5,16]
    const float* __restrict__ b_hh,   // [5,16]
    const float* __restrict__ w_lin,  // [1,4]
    const float* __restrict__ b_lin,  // [1]
    const float* __restrict__ w_fc,   // [5,610]
    const float* __restrict__ b_fc,   // [5]
    float* __restrict__ out)          // [128,5]
{
    __shared__ float lds_x[4 * SEQ * 2 + 24];   // [4 rows][610][2] + pad
    __shared__ float lds_wfc[5 * SEQ + 16];     // [5][610] + pad

    const int lane = threadIdx.x;
    const int half = lane >> 5;
    const int r    = lane & 31;
    const int l    = r >> 2;
    const int k    = r & 3;
    const int lw   = l > 4 ? 4 : l;
    const bool is_l0 = (l == 0);
    const int rowA = blockIdx.x * 4 + half;
    const int rowB = rowA + 2;

    // ---- stage 4 x-rows + w_fc into LDS, coalesced ----
    #pragma unroll
    for (int rr = 0; rr < 4; ++rr) {
        const float4* src = (const float4*)(x + (size_t)(blockIdx.x * 4 + rr) * (SEQ * 2));
        float4* dst = (float4*)&lds_x[rr * (SEQ * 2)];
        for (int i = lane; i < (SEQ * 2) / 4; i += 64) dst[i] = src[i];
    }
    {
        const float2* src = (const float2*)w_fc;
        float2* dst = (float2*)lds_wfc;
        for (int i = lane; i < (5 * SEQ) / 2; i += 64) dst[i] = src[i];
    }
    __syncthreads();

    // ---- per-lane weights, pre-scaled by log2e, splatted to v2f ----
    v2f wi2[4][4], wh2[4][4], bias2[4];
    #pragma unroll
    for (int j = 0; j < 4; ++j) {
        const float s = (j == 2) ? 2.8853900817779268f   // +2*log2(e) for g
                                 : -1.4426950408889634f; // -log2(e) for i,f,o
        const int row = j * H + k;
        float a0, a1, a2, a3;
        if (lw == 0) {
            a0 = w_ih0[row * 2 + 0] * s; a1 = w_ih0[row * 2 + 1] * s; a2 = 0.f; a3 = 0.f;
        } else {
            const float4 v = *(const float4*)&w_ih[((lw - 1) * 16 + row) * 4];
            a0 = v.x * s; a1 = v.y * s; a2 = v.z * s; a3 = v.w * s;
        }
        wi2[j][0] = (v2f){a0, a0}; wi2[j][1] = (v2f){a1, a1};
        wi2[j][2] = (v2f){a2, a2}; wi2[j][3] = (v2f){a3, a3};
        const float4 u = *(const float4*)&w_hh[(lw * 16 + row) * 4];
        wh2[j][0] = (v2f){u.x * s, u.x * s}; wh2[j][1] = (v2f){u.y * s, u.y * s};
        wh2[j][2] = (v2f){u.z * s, u.z * s}; wh2[j][3] = (v2f){u.w * s, u.w * s};
        const float bb = (b_ih[lw * 16 + row] + b_hh[lw * 16 + row]) * s;
        bias2[j] = (v2f){bb, bb};
    }
    v2f wl2[4], bl2;
    #pragma unroll
    for (int j = 0; j < 4; ++j) wl2[j] = (v2f){w_lin[j], w_lin[j]};
    bl2 = (v2f){b_lin[0], b_lin[0]};

    const int xbA = half * (SEQ * 2);
    const int xbB = (2 + half) * (SEQ * 2);
    const int wbase  = k * SEQ;
    const int w4base = 4 * SEQ;
    const v2f z2 = (v2f){0.f, 0.f};

    // ---- state (v2f = {stream A, stream B}) ----
    v2f c2 = z2, q0 = z2, q1 = z2, q2 = z2, q3 = z2;
    v2f accA2 = z2, accB2 = z2, wfcA2 = z2, wfcB2 = z2;
    v2f pre0, pre1, pre2, pre3;
    {   // pre for tick 0: x(0) on layer 0, zeros elsewhere
        v2f xq0 = (v2f){is_l0 ? lds_x[xbA + 0] : 0.f, is_l0 ? lds_x[xbB + 0] : 0.f};
        v2f xq1 = (v2f){is_l0 ? lds_x[xbA + 1] : 0.f, is_l0 ? lds_x[xbB + 1] : 0.f};
        pre0 = FMA2(wi2[0][1], xq1, FMA2(wi2[0][0], xq0, bias2[0]));
        pre1 = FMA2(wi2[1][1], xq1, FMA2(wi2[1][0], xq0, bias2[1]));
        pre2 = FMA2(wi2[2][1], xq1, FMA2(wi2[2][0], xq0, bias2[2]));
        pre3 = FMA2(wi2[3][1], xq1, FMA2(wi2[3][0], xq0, bias2[3]));
    }

    // ---- shared tick core: gates -> c -> h -> DPPs -> installs.
    // GATED adds validity selects (head ticks only). nx/wfc installs come from
    // the named registers passed in.
    #define CORE(tau_, GATED, NXA0, NXA1, NXB0, NXB1, NWA, NWB)                       \
    {                                                                                 \
        v2f G0 = FMA2(wh2[0][3], q3, FMA2(wh2[0][2], q2, FMA2(wh2[0][1], q1, FMA2(wh2[0][0], q0, pre0)))); \
        v2f G1 = FMA2(wh2[1][3], q3, FMA2(wh2[1][2], q2, FMA2(wh2[1][1], q1, FMA2(wh2[1][0], q0, pre1)))); \
        v2f G2 = FMA2(wh2[2][3], q3, FMA2(wh2[2][2], q2, FMA2(wh2[2][1], q1, FMA2(wh2[2][0], q0, pre2)))); \
        v2f G3 = FMA2(wh2[3][3], q3, FMA2(wh2[3][2], q2, FMA2(wh2[3][1], q1, FMA2(wh2[3][0], q0, pre3)))); \
        v2f Ai = exp22(G0) + 1.f;                                                     \
        v2f Af = exp22(G1) + 1.f;                                                     \
        v2f Dg = exp22(G2) + 1.f;                                                     \
        v2f Ao = exp22(G3) + 1.f;                                                     \
        v2f M   = Ai * Dg;                                                            \
        v2f den = M * Af;                                                             \
        v2f num = FMA2(c2, M, Af * (Dg - 2.f));                                       \
        v2f cn  = num * rcp2(den);                                                    \
        unsigned tt = (unsigned)((tau_) - l);                                         \
        c2 = (GATED) ? ((tt < SEQ) ? cn : z2) : cn;                                   \
        v2f Dc = exp22(c2 * 2.8853900817779268f) + 1.f;                               \
        v2f h2 = (Dc - 2.f) * rcp2(Ao * Dc);                                          \
        v2f nq0 = dpp2<0x00, true>(z2, h2);                                           \
        v2f nq1 = dpp2<0x55, true>(z2, h2);                                           \
        v2f nq2 = dpp2<0xAA, true>(z2, h2);                                           \
        v2f nq3 = dpp2<0xFF, true>(z2, h2);                                           \
        v2f p0 = dpp2<0x142, true>(z2, nq0); p0 = dpp2<0x114, false>(p0, nq0);        \
        v2f p1 = dpp2<0x142, true>(z2, nq1); p1 = dpp2<0x114, false>(p1, nq1);        \
        v2f p2 = dpp2<0x142, true>(z2, nq2); p2 = dpp2<0x114, false>(p2, nq2);        \
        v2f p3 = dpp2<0x142, true>(z2, nq3); p3 = dpp2<0x114, false>(p3, nq3);        \
        v2f nx0 = (v2f){NXA0, NXB0};                                                  \
        v2f nx1 = (v2f){NXA1, NXB1};                                                  \
        v2f xq0 = is_l0 ? nx0 : p0;                                                   \
        v2f xq1 = is_l0 ? nx1 : p1;                                                   \
        pre0 = FMA2(wi2[0][3], p3, FMA2(wi2[0][2], p2, FMA2(wi2[0][1], xq1, FMA2(wi2[0][0], xq0, bias2[0])))); \
        pre1 = FMA2(wi2[1][3], p3, FMA2(wi2[1][2], p2, FMA2(wi2[1][1], xq1, FMA2(wi2[1][0], xq0, bias2[1])))); \
        pre2 = FMA2(wi2[2][3], p3, FMA2(wi2[2][2], p2, FMA2(wi2[2][1], xq1, FMA2(wi2[2][0], xq0, bias2[2])))); \
        pre3 = FMA2(wi2[3][3], p3, FMA2(wi2[3][2], p2, FMA2(wi2[3][1], xq1, FMA2(wi2[3][0], xq0, bias2[3])))); \
        v2f tval = FMA2(nq3, wl2[3], bl2);                                            \
        tval = FMA2(nq2, wl2[2], tval);                                               \
        tval = FMA2(nq1, wl2[1], tval);                                               \
        tval = FMA2(nq0, wl2[0], tval);                                               \
        if (GATED) tval = (tt < SEQ) ? tval : z2;                                     \
        accA2 = FMA2(tval, wfcA2, accA2);                                             \
        accB2 = FMA2(tval, wfcB2, accB2);                                             \
        q0 = nq0; q1 = nq1; q2 = nq2; q3 = nq3;                                       \
        wfcA2 = (v2f){NWA, NWA};                                                      \
        wfcB2 = (v2f){NWB, NWB};                                                      \
    }

    // ---- gated head (ticks 0..3): direct distance-1 loads, clamped indices ----
    for (int tau = 0; tau < 4; ++tau) {
        const int tn = tau + 1;
        int t4 = tau - 3; t4 = t4 < 0 ? 0 : t4;
        const float nxA0_ = lds_x[xbA + tn * 2], nxA1_ = lds_x[xbA + tn * 2 + 1];
        const float nxB0_ = lds_x[xbB + tn * 2], nxB1_ = lds_x[xbB + tn * 2 + 1];
        const float nwA_ = lds_wfc[wbase + t4], nwB_ = lds_wfc[w4base + t4];
        CORE(tau, true, nxA0_, nxA1_, nxB0_, nxB1_, nwA_, nwB_);
    }

    // ---- prime distance-2 prefetch slots ----
    // slot0 consumed at tick 4: installs x[5], wfc[1]; slot1 at tick 5: x[6], wfc[2]
    float s0_nxA0 = lds_x[xbA + 5 * 2], s0_nxA1 = lds_x[xbA + 5 * 2 + 1];
    float s0_nxB0 = lds_x[xbB + 5 * 2], s0_nxB1 = lds_x[xbB + 5 * 2 + 1];
    float s0_wA = lds_wfc[wbase + 1], s0_wB = lds_wfc[w4base + 1];
    float s1_nxA0 = lds_x[xbA + 6 * 2], s1_nxA1 = lds_x[xbA + 6 * 2 + 1];
    float s1_nxB0 = lds_x[xbB + 6 * 2], s1_nxB1 = lds_x[xbB + 6 * 2 + 1];
    float s1_wA = lds_wfc[wbase + 2], s1_wB = lds_wfc[w4base + 2];

    // ---- clean main loop, 2 ticks/iter, distance-2 prefetch rotation.
    // Tick tau issues loads for x[tau+3], wfc[tau-1] into its slot (used 2 ticks
    // later). Tail junk in layers 0-3 needs 4 ticks to reach layer 4; loop ends
    // first. All over-reads land in the padded LDS arrays.
    #define TICK(tau_, SNXA0, SNXA1, SNXB0, SNXB1, SWA, SWB)                          \
    {                                                                                 \
        const int tpf = (tau_) + 3;                                                   \
        const float t_nxA0 = lds_x[xbA + tpf * 2], t_nxA1 = lds_x[xbA + tpf * 2 + 1]; \
        const float t_nxB0 = lds_x[xbB + tpf * 2], t_nxB1 = lds_x[xbB + tpf * 2 + 1]; \
        const float t_wA = lds_wfc[wbase + (tau_) - 1];                               \
        const float t_wB = lds_wfc[w4base + (tau_) - 1];                              \
        CORE(tau_, false, SNXA0, SNXA1, SNXB0, SNXB1, SWA, SWB);                      \
        SNXA0 = t_nxA0; SNXA1 = t_nxA1; SNXB0 = t_nxB0; SNXB1 = t_nxB1;               \
        SWA = t_wA; SWB = t_wB;                                                       \
    }

    for (int tau = 4; tau < TICKS; tau += 2) {
        TICK(tau,     s0_nxA0, s0_nxA1, s0_nxB0, s0_nxB1, s0_wA, s0_wB);
        TICK(tau + 1, s1_nxA0, s1_nxA1, s1_nxB0, s1_nxB1, s1_wA, s1_wB);
    }
    #undef TICK
    #undef CORE

    if (r >= 16 && r < 20) {                // layer-4 lanes
        out[rowA * 5 + k] = accA2[0] + b_fc[k];
        out[rowB * 5 + k] = accA2[1] + b_fc[k];
        if (k == 0) {
            out[rowA * 5 + 4] = accB2[0] + b_fc[4];
            out[rowB * 5 + 4] = accB2[1] + b_fc[4];
        }
    }
}

extern "C" void kernel_launch(void* const* d_in, const int* in_sizes, int n_in,
                              void* d_out, int out_size, void* d_ws, size_t ws_size,
                              hipStream_t stream)
{
    const float* x     = (const float*)d_in[0];
    const float* w_ih0 = (const float*)d_in[1];
    const float* w_ih  = (const float*)d_in[2];
    const float* w_hh  = (const float*)d_in[3];
    const float* b_ih  = (const float*)d_in[4];
    const float* b_hh  = (const float*)d_in[5];
    const float* w_lin = (const float*)d_in[6];
    const float* b_lin = (const float*)d_in[7];
    const float* w_fc  = (const float*)d_in[8];
    const float* b_fc  = (const float*)d_in[9];
    float* out = (float*)d_out;

    lstm_2s_kernel<<<dim3(BATCH / 4), dim3(64), 0, stream>>>(
        x, w_ih0, w_ih, w_hh, b_ih, b_hh, w_lin, b_lin, w_fc, b_fc, out);
}

// Round 10
// 176.579 us; speedup vs baseline: 1.2617x; 1.2617x over previous
//
#include <hip/hip_runtime.h>
#include <math.h>

#define H 4
#define NL 5
#define SEQ 610
#define BATCH 128
// 2-tick per-layer handoff: layer l computes timestep t = tau - 2*l.
// tau = 0..618: layer4 finishes t=609 at tau=617; its h is consumed by the
// output head (acc) one tick later, at tau=618.
#define NITER 619
#define HEAD 10      // gated head ticks (covers t<0 for all layers and t4<0)

// update_dpp on float. CTRL: quad_perm 0x00/0x55/0xAA/0xFF, row_shr:4 0x114,
// row_bcast15 0x142. BC: true -> 0 on invalid src, false -> keep `old`.
template<int CTRL, bool BC>
__device__ __forceinline__ float dpp1(float old_, float src) {
    return __int_as_float(__builtin_amdgcn_update_dpp(
        __float_as_int(old_), __float_as_int(src), CTRL, 0xF, 0xF, BC));
}

// Lane layout (per 32-lane half = one batch row):
//   r = lane&31; layers 0-3 = quads 0-3 (r=0..15), layer 4 = lanes 16-19
//   (quad 0 of the next DPP row); r>=20 computes junk.
//
// Iteration tau:
//   CHAIN (loop-carried, stall-prone): gates = pre(seed) + Wh·q -> c -> h ->
//     quad-DPP -> new q.   pre was computed LAST iteration -> ready at start.
//   BURST (depends ONLY on iter-start q = h(tau-1), freely schedulable into
//     the chain's stall windows): p = cross-layer shift of old q; pre for
//     chain(tau+1); output head tval/acc; LDS loads.
// The 2-tick handoff makes the burst independent of this tick's chain output,
// which is what R6 lacked (its pre was the tail of an h-dependent burst).
__global__ __launch_bounds__(64) void lstm_sp_kernel(
    const float* __restrict__ x,      // [128,610,2]
    const float* __restrict__ w_ih0,  // [16,2]
    const float* __restrict__ w_ih,   // [4,16,4]
    const float* __restrict__ w_hh,   // [5,16,4]
    const float* __restrict__ b_ih,   // [5,16]
    const float* __restrict__ b_hh,   // [5,16]
    const float* __restrict__ w_lin,  // [1,4]
    const float* __restrict__ b_lin,  // [1]
    const float* __restrict__ w_fc,   // [5,610]
    const float* __restrict__ b_fc,   // [5]
    float* __restrict__ out)          // [128,5]
{
    __shared__ float lds_x[2 * SEQ * 2 + 24];   // [2][610][2] + pad (clean-tail over-reads)
    __shared__ float lds_wfcp[4 * SEQ * 2];     // [4][610][2] = {wfc[k][t], wfc[4][t]}

    const int lane = threadIdx.x;
    const int half = lane >> 5;
    const int r    = lane & 31;
    const int l    = r >> 2;
    const int k    = r & 3;
    const int lw   = l > 4 ? 4 : l;
    const bool is_l0 = (l == 0);
    const int row  = blockIdx.x * 2 + half;

    // ---- stage x rows + paired w_fc into LDS, coalesced ----
    #pragma unroll
    for (int hh = 0; hh < 2; ++hh) {
        const float4* src = (const float4*)(x + (size_t)(blockIdx.x * 2 + hh) * (SEQ * 2));
        float4* dst = (float4*)&lds_x[hh * (SEQ * 2)];
        for (int i = lane; i < (SEQ * 2) / 4; i += 64) dst[i] = src[i];
    }
    #pragma unroll
    for (int kk = 0; kk < 4; ++kk) {
        for (int t = lane; t < SEQ; t += 64) {
            lds_wfcp[(kk * SEQ + t) * 2 + 0] = w_fc[kk * SEQ + t];
            lds_wfcp[(kk * SEQ + t) * 2 + 1] = w_fc[4 * SEQ + t];
        }
    }
    __syncthreads();

    // ---- per-lane weights (gate j of unit k, layer lw), pre-scaled by log2e ----
    float wi[4][4], wh[4][4], bias[4];
    #pragma unroll
    for (int j = 0; j < 4; ++j) {
        const float s = (j == 2) ? 2.8853900817779268f   // +2*log2(e) for g
                                 : -1.4426950408889634f; // -log2(e) for i,f,o
        const int wrow = j * H + k;
        if (lw == 0) {
            wi[j][0] = w_ih0[wrow * 2 + 0] * s;
            wi[j][1] = w_ih0[wrow * 2 + 1] * s;
            wi[j][2] = 0.f; wi[j][3] = 0.f;
        } else {
            const float4 v = *(const float4*)&w_ih[((lw - 1) * 16 + wrow) * 4];
            wi[j][0] = v.x * s; wi[j][1] = v.y * s; wi[j][2] = v.z * s; wi[j][3] = v.w * s;
        }
        const float4 u = *(const float4*)&w_hh[(lw * 16 + wrow) * 4];
        wh[j][0] = u.x * s; wh[j][1] = u.y * s; wh[j][2] = u.z * s; wh[j][3] = u.w * s;
        bias[j] = (b_ih[lw * 16 + wrow] + b_hh[lw * 16 + wrow]) * s;
    }
    const float wl0 = w_lin[0], wl1 = w_lin[1], wl2 = w_lin[2], wl3 = w_lin[3];
    const float bl  = b_lin[0];

    const int xb     = half * (SEQ * 2);
    const int wpbase = k * SEQ;

    // ---- state ----
    float c = 0.f;
    float q0 = 0.f, q1 = 0.f, q2 = 0.f, q3 = 0.f;   // h(tau-1), own layer, gathered
    float accA = 0.f, accB = 0.f;
    float pre0, pre1, pre2, pre3;                    // for chain(tau=0)
    {
        const float2 xv0 = *(const float2*)&lds_x[xb];
        const float xq0 = is_l0 ? xv0.x : 0.f;
        const float xq1 = is_l0 ? xv0.y : 0.f;
        pre0 = fmaf(wi[0][1], xq1, fmaf(wi[0][0], xq0, bias[0]));
        pre1 = fmaf(wi[1][1], xq1, fmaf(wi[1][0], xq0, bias[1]));
        pre2 = fmaf(wi[2][1], xq1, fmaf(wi[2][0], xq0, bias[2]));
        pre3 = fmaf(wi[3][1], xq1, fmaf(wi[3][0], xq0, bias[3]));
    }

    #define TICK_BODY(tau_, GATED)                                                    \
    {                                                                                 \
        /* loads (independent; scheduler hoists to fill) */                           \
        const float2 nx = *(const float2*)&lds_x[xb + ((tau_) + 1) * 2];              \
        int t4 = (tau_) - 9;                                                          \
        if (GATED) t4 = t4 < 0 ? 0 : t4;                                              \
        const float2 wv = *(const float2*)&lds_wfcp[(wpbase + t4) * 2];               \
        /* iter-start q (SSA copies, no cost) */                                      \
        const float oq0 = q0, oq1 = q1, oq2 = q2, oq3 = q3;                           \
        /* ---- CHAIN: gates (pre seed, ready) -> c -> h -> quad DPP ---- */          \
        const float g0 = fmaf(wh[0][3], oq3, fmaf(wh[0][2], oq2, fmaf(wh[0][1], oq1, fmaf(wh[0][0], oq0, pre0)))); \
        const float g1 = fmaf(wh[1][3], oq3, fmaf(wh[1][2], oq2, fmaf(wh[1][1], oq1, fmaf(wh[1][0], oq0, pre1)))); \
        const float g2 = fmaf(wh[2][3], oq3, fmaf(wh[2][2], oq2, fmaf(wh[2][1], oq1, fmaf(wh[2][0], oq0, pre2)))); \
        const float g3 = fmaf(wh[3][3], oq3, fmaf(wh[3][2], oq2, fmaf(wh[3][1], oq1, fmaf(wh[3][0], oq0, pre3)))); \
        const float Ai = 1.f + __builtin_amdgcn_exp2f(g0);                            \
        const float Af = 1.f + __builtin_amdgcn_exp2f(g1);                            \
        const float Dg = 1.f + __builtin_amdgcn_exp2f(g2);                            \
        const float Ao = 1.f + __builtin_amdgcn_exp2f(g3);                            \
        const float M   = Ai * Dg;                                                    \
        const float den = M * Af;                                                     \
        const float num = fmaf(c, M, Af * (Dg - 2.f));                                \
        float cn = num * __builtin_amdgcn_rcpf(den);                                  \
        if (GATED) { const unsigned tt = (unsigned)((tau_) - 2 * l);                  \
                     cn = (tt < SEQ) ? cn : 0.f; }                                    \
        c = cn;                                                                       \
        const float Dc = 1.f + __builtin_amdgcn_exp2f(c * 2.8853900817779268f);       \
        const float h  = (Dc - 2.f) * __builtin_amdgcn_rcpf(Ao * Dc);                 \
        q0 = dpp1<0x00, true>(0.f, h);                                                \
        q1 = dpp1<0x55, true>(0.f, h);                                                \
        q2 = dpp1<0xAA, true>(0.f, h);                                                \
        q3 = dpp1<0xFF, true>(0.f, h);                                                \
        /* ---- BURST: depends only on oq / loads (fills chain stalls) ---- */        \
        float p0 = dpp1<0x142, true>(0.f, oq0); p0 = dpp1<0x114, false>(p0, oq0);     \
        float p1 = dpp1<0x142, true>(0.f, oq1); p1 = dpp1<0x114, false>(p1, oq1);     \
        float p2 = dpp1<0x142, true>(0.f, oq2); p2 = dpp1<0x114, false>(p2, oq2);     \
        float p3 = dpp1<0x142, true>(0.f, oq3); p3 = dpp1<0x114, false>(p3, oq3);     \
        const float xq0 = is_l0 ? nx.x : p0;                                          \
        const float xq1 = is_l0 ? nx.y : p1;                                          \
        pre0 = fmaf(wi[0][3], p3, fmaf(wi[0][2], p2, fmaf(wi[0][1], xq1, fmaf(wi[0][0], xq0, bias[0])))); \
        pre1 = fmaf(wi[1][3], p3, fmaf(wi[1][2], p2, fmaf(wi[1][1], xq1, fmaf(wi[1][0], xq0, bias[1])))); \
        pre2 = fmaf(wi[2][3], p3, fmaf(wi[2][2], p2, fmaf(wi[2][1], xq1, fmaf(wi[2][0], xq0, bias[2])))); \
        pre3 = fmaf(wi[3][3], p3, fmaf(wi[3][2], p2, fmaf(wi[3][1], xq1, fmaf(wi[3][0], xq0, bias[3])))); \
        float tval = fmaf(oq0, wl0, fmaf(oq1, wl1, fmaf(oq2, wl2, fmaf(oq3, wl3, bl)))); \
        if (GATED) tval = ((unsigned)((tau_) - 9) < SEQ) ? tval : 0.f;                \
        accA = fmaf(tval, wv.x, accA);                                                \
        accB = fmaf(tval, wv.y, accB);                                                \
    }

    // gated head: layers warm up (t<0 forced to 0), acc gated until t4>=0
    for (int tau = 0; tau < HEAD; ++tau) TICK_BODY(tau, true);
    // clean body: no gates. Layer-l junk timesteps (t>609) start at tau=610 on
    // layer 0 and need 8 ticks to reach layer 4's h, whose head-consumption
    // would be tau=619 -- after the loop ends. wfc index t4 <= 609 exactly;
    // x over-reads (up to idx 1239 per row) stay inside the padded lds_x.
    #pragma unroll 2
    for (int tau = HEAD; tau < NITER; ++tau) TICK_BODY(tau, false);
    #undef TICK_BODY

    if (r >= 16 && r < 20) {                // layer-4 lanes
        out[row * 5 + k] = accA + b_fc[k];
        if (k == 0) out[row * 5 + 4] = accB + b_fc[4];
    }
}

extern "C" void kernel_launch(void* const* d_in, const int* in_sizes, int n_in,
                              void* d_out, int out_size, void* d_ws, size_t ws_size,
                              hipStream_t stream)
{
    const float* x     = (const float*)d_in[0];
    const float* w_ih0 = (const float*)d_in[1];
    const float* w_ih  = (const float*)d_in[2];
    const float* w_hh  = (const float*)d_in[3];
    const float* b_ih  = (const float*)d_in[4];
    const float* b_hh  = (const float*)d_in[5];
    const float* w_lin = (const float*)d_in[6];
    const float* b_lin = (const float*)d_in[7];
    const float* w_fc  = (const float*)d_in[8];
    const float* b_fc  = (const float*)d_in[9];
    float* out = (float*)d_out;

    lstm_sp_kernel<<<dim3(BATCH / 2), dim3(64), 0, stream>>>(
        x, w_ih0, w_ih, w_hh, b_ih, b_hh, w_lin, b_lin, w_fc, b_fc, out);
}

// Round 11
// 158.925 us; speedup vs baseline: 1.4019x; 1.1111x over previous
//
#include <hip/hip_runtime.h>
#include <math.h>

#define H 4
#define NL 5
#define SEQ 610
#define BATCH 128
// 2-tick per-layer handoff: layer l computes timestep t = tau - 2*l.
#define NITER 619
#define HEAD 16      // gated head ticks
#define TAIL0 616    // HEAD + 75*8 ; ticks 616..618 are the gated tail

typedef float v2f __attribute__((ext_vector_type(2)));

#if __has_builtin(__builtin_elementwise_fma)
#define FMA2(a, b, c) __builtin_elementwise_fma((a), (b), (c))
#else
static __device__ __forceinline__ v2f FMA2(v2f a, v2f b, v2f c) {
    v2f r; r[0] = fmaf(a[0], b[0], c[0]); r[1] = fmaf(a[1], b[1], c[1]); return r;
}
#endif

static __device__ __forceinline__ v2f splat2(float a) { v2f r; r[0] = a; r[1] = a; return r; }

// update_dpp on float. CTRL: quad_perm 0x00/0x55/0xAA/0xFF, row_shr:4 0x114,
// row_bcast15 0x142. BC: true -> 0 on invalid src, false -> keep `old`.
template<int CTRL, bool BC>
__device__ __forceinline__ float dpp1(float old_, float src) {
    return __int_as_float(__builtin_amdgcn_update_dpp(
        __float_as_int(old_), __float_as_int(src), CTRL, 0xF, 0xF, BC));
}

// Lane layout (per 32-lane half = one batch row):
//   r = lane&31; layers 0-3 = quads 0-3 (r=0..15), layer 4 = lanes 16-19;
//   r>=20 computes junk (never written out).
// Gate math packed as pairs {gate0,gate1} and {gate2,gate3} -> v_pk_fma_f32.
// x / w_fc consumed from 8-tick register chunks (LDS latency amortized 8x).
__global__ __launch_bounds__(64) void lstm_pk_kernel(
    const float* __restrict__ x,      // [128,610,2]
    const float* __restrict__ w_ih0,  // [16,2]
    const float* __restrict__ w_ih,   // [4,16,4]
    const float* __restrict__ w_hh,   // [5,16,4]
    const float* __restrict__ b_ih,   // [5,16]
    const float* __restrict__ b_hh,   // [5,16]
    const float* __restrict__ w_lin,  // [1,4]
    const float* __restrict__ b_lin,  // [1]
    const float* __restrict__ w_fc,   // [5,610]
    const float* __restrict__ b_fc,   // [5]
    float* __restrict__ out)          // [128,5]
{
    __shared__ float lds_x[2 * SEQ * 2 + 32];   // [2][610][2] + pad (tail over-reads)
    __shared__ float lds_wfcp[4 * SEQ * 2 + 8]; // [4][610][2] = {wfc[k][t], wfc[4][t]}

    const int lane = threadIdx.x;
    const int half = lane >> 5;
    const int r    = lane & 31;
    const int l    = r >> 2;
    const int k    = r & 3;
    const int lw   = l > 4 ? 4 : l;
    const bool is_l0 = (l == 0);
    const int row  = blockIdx.x * 2 + half;

    // ---- stage x rows + paired w_fc into LDS, coalesced ----
    #pragma unroll
    for (int hh = 0; hh < 2; ++hh) {
        const float4* src = (const float4*)(x + (size_t)(blockIdx.x * 2 + hh) * (SEQ * 2));
        float4* dst = (float4*)&lds_x[hh * (SEQ * 2)];
        for (int i = lane; i < (SEQ * 2) / 4; i += 64) dst[i] = src[i];
    }
    #pragma unroll
    for (int kk = 0; kk < 4; ++kk) {
        for (int t = lane; t < SEQ; t += 64) {
            lds_wfcp[(kk * SEQ + t) * 2 + 0] = w_fc[kk * SEQ + t];
            lds_wfcp[(kk * SEQ + t) * 2 + 1] = w_fc[4 * SEQ + t];
        }
    }
    __syncthreads();

    // ---- per-lane weights, pre-scaled by log2e, packed as gate pairs ----
    // pair01 = {gate i, gate f}; pair23 = {gate g, gate o}
    v2f wip01[4], wip23[4], whp01[4], whp23[4], b01, b23;
    {
        float wi[4][4], wh[4][4], bias[4];
        #pragma unroll
        for (int j = 0; j < 4; ++j) {
            const float s = (j == 2) ? 2.8853900817779268f   // +2*log2(e) for g
                                     : -1.4426950408889634f; // -log2(e) for i,f,o
            const int wrow = j * H + k;
            if (lw == 0) {
                wi[j][0] = w_ih0[wrow * 2 + 0] * s;
                wi[j][1] = w_ih0[wrow * 2 + 1] * s;
                wi[j][2] = 0.f; wi[j][3] = 0.f;
            } else {
                const float4 v = *(const float4*)&w_ih[((lw - 1) * 16 + wrow) * 4];
                wi[j][0] = v.x * s; wi[j][1] = v.y * s; wi[j][2] = v.z * s; wi[j][3] = v.w * s;
            }
            const float4 u = *(const float4*)&w_hh[(lw * 16 + wrow) * 4];
            wh[j][0] = u.x * s; wh[j][1] = u.y * s; wh[j][2] = u.z * s; wh[j][3] = u.w * s;
            bias[j] = (b_ih[lw * 16 + wrow] + b_hh[lw * 16 + wrow]) * s;
        }
        #pragma unroll
        for (int m = 0; m < 4; ++m) {
            wip01[m][0] = wi[0][m]; wip01[m][1] = wi[1][m];
            wip23[m][0] = wi[2][m]; wip23[m][1] = wi[3][m];
            whp01[m][0] = wh[0][m]; whp01[m][1] = wh[1][m];
            whp23[m][0] = wh[2][m]; whp23[m][1] = wh[3][m];
        }
        b01[0] = bias[0]; b01[1] = bias[1];
        b23[0] = bias[2]; b23[1] = bias[3];
    }
    const float wl0 = w_lin[0], wl1 = w_lin[1], wl2 = w_lin[2], wl3 = w_lin[3];
    const float bl  = b_lin[0];

    const int xb     = half * (SEQ * 2);
    const int wpbase = k * SEQ;

    // ---- state ----
    float c = 0.f;
    float q0 = 0.f, q1 = 0.f, q2 = 0.f, q3 = 0.f;   // h(tau-1) of own layer, gathered
    float accA = 0.f, accB = 0.f;
    v2f pre01, pre23;                                // gate pre-activations for chain(tau)
    {
        const float2 xv0 = *(const float2*)&lds_x[xb];
        const float xs0 = is_l0 ? xv0.x : 0.f;
        const float xs1 = is_l0 ? xv0.y : 0.f;
        pre01 = FMA2(wip01[1], splat2(xs1), FMA2(wip01[0], splat2(xs0), b01));
        pre23 = FMA2(wip23[1], splat2(xs1), FMA2(wip23[0], splat2(xs0), b23));
    }

    #define TICK_CORE(tau_, GATED, NXv, WVv)                                          \
    {                                                                                 \
        const float oq0 = q0, oq1 = q1, oq2 = q2, oq3 = q3;                           \
        /* ---- CHAIN: packed gates -> c -> h -> quad DPP ---- */                     \
        v2f G01 = FMA2(whp01[3], splat2(oq3), FMA2(whp01[2], splat2(oq2),             \
                  FMA2(whp01[1], splat2(oq1), FMA2(whp01[0], splat2(oq0), pre01)))); \
        v2f G23 = FMA2(whp23[3], splat2(oq3), FMA2(whp23[2], splat2(oq2),             \
                  FMA2(whp23[1], splat2(oq1), FMA2(whp23[0], splat2(oq0), pre23)))); \
        const float Ai = 1.f + __builtin_amdgcn_exp2f(G01[0]);                        \
        const float Af = 1.f + __builtin_amdgcn_exp2f(G01[1]);                        \
        const float Dg = 1.f + __builtin_amdgcn_exp2f(G23[0]);                        \
        const float Ao = 1.f + __builtin_amdgcn_exp2f(G23[1]);                        \
        const float M   = Ai * Dg;                                                    \
        const float den = M * Af;                                                     \
        const float num = fmaf(c, M, Af * (Dg - 2.f));                                \
        float cn = num * __builtin_amdgcn_rcpf(den);                                  \
        if (GATED) { const unsigned tt = (unsigned)((tau_) - 2 * l);                  \
                     cn = (tt < SEQ) ? cn : 0.f; }                                    \
        c = cn;                                                                       \
        const float Dc = 1.f + __builtin_amdgcn_exp2f(c * 2.8853900817779268f);       \
        const float hv = (Dc - 2.f) * __builtin_amdgcn_rcpf(Ao * Dc);                 \
        q0 = dpp1<0x00, true>(0.f, hv);                                               \
        q1 = dpp1<0x55, true>(0.f, hv);                                               \
        q2 = dpp1<0xAA, true>(0.f, hv);                                               \
        q3 = dpp1<0xFF, true>(0.f, hv);                                               \
        /* ---- BURST (depends only on oq / chunk regs) ---- */                       \
        float p0 = dpp1<0x142, true>(0.f, oq0); p0 = dpp1<0x114, false>(p0, oq0);     \
        float p1 = dpp1<0x142, true>(0.f, oq1); p1 = dpp1<0x114, false>(p1, oq1);     \
        float p2 = dpp1<0x142, true>(0.f, oq2); p2 = dpp1<0x114, false>(p2, oq2);     \
        float p3 = dpp1<0x142, true>(0.f, oq3); p3 = dpp1<0x114, false>(p3, oq3);     \
        const float xs0 = is_l0 ? (NXv).x : p0;                                       \
        const float xs1 = is_l0 ? (NXv).y : p1;                                       \
        pre01 = FMA2(wip01[3], splat2(p3), FMA2(wip01[2], splat2(p2),                 \
                FMA2(wip01[1], splat2(xs1), FMA2(wip01[0], splat2(xs0), b01))));      \
        pre23 = FMA2(wip23[3], splat2(p3), FMA2(wip23[2], splat2(p2),                 \
                FMA2(wip23[1], splat2(xs1), FMA2(wip23[0], splat2(xs0), b23))));      \
        float tval = fmaf(oq0, wl0, fmaf(oq1, wl1, fmaf(oq2, wl2, fmaf(oq3, wl3, bl)))); \
        if (GATED) tval = ((unsigned)((tau_) - 9) < SEQ) ? tval : 0.f;                \
        accA = fmaf(tval, (WVv).x, accA);                                             \
        accB = fmaf(tval, (WVv).y, accB);                                             \
    }

    // ---- gated head: per-tick LDS loads, clamped indices ----
    for (int tau = 0; tau < HEAD; ++tau) {
        const float2 nx = *(const float2*)&lds_x[xb + (tau + 1) * 2];
        int t4 = tau - 9; t4 = t4 < 0 ? 0 : t4;
        const float2 wv = *(const float2*)&lds_wfcp[(wpbase + t4) * 2];
        TICK_CORE(tau, true, nx, wv);
    }

    // ---- clean body: 75 chunks x 8 ticks; loads batched per chunk into regs.
    // Junk timesteps (t>609) on layers 0-3 cannot reach layer-4's consumed h
    // before the loop ends (needs 8+ ticks); wfc index tau-9 stays in [7,606];
    // x over-reads stay inside the padded lds_x.
    for (int ch = 0; ch < 75; ++ch) {
        const int tau0 = HEAD + ch * 8;
        float2 xc[8], wc[8];
        #pragma unroll
        for (int i = 0; i < 8; ++i) {
            xc[i] = *(const float2*)&lds_x[xb + (tau0 + 1 + i) * 2];
            wc[i] = *(const float2*)&lds_wfcp[(wpbase + tau0 + i - 9) * 2];
        }
        #pragma unroll
        for (int i = 0; i < 8; ++i) {
            TICK_CORE(tau0 + i, false, xc[i], wc[i]);
        }
    }

    // ---- gated tail (ticks 616..618): gating conditions are all benign here
    // (layer-4 t stays < SEQ; tval window valid), junk layers harmlessly zeroed.
    for (int tau = TAIL0; tau < NITER; ++tau) {
        const float2 nx = *(const float2*)&lds_x[xb + (tau + 1) * 2];
        const float2 wv = *(const float2*)&lds_wfcp[(wpbase + tau - 9) * 2];
        TICK_CORE(tau, true, nx, wv);
    }
    #undef TICK_CORE

    if (r >= 16 && r < 20) {                // layer-4 lanes
        out[row * 5 + k] = accA + b_fc[k];
        if (k == 0) out[row * 5 + 4] = accB + b_fc[4];
    }
}

extern "C" void kernel_launch(void* const* d_in, const int* in_sizes, int n_in,
                              void* d_out, int out_size, void* d_ws, size_t ws_size,
                              hipStream_t stream)
{
    const float* x     = (const float*)d_in[0];
    const float* w_ih0 = (const float*)d_in[1];
    const float* w_ih  = (const float*)d_in[2];
    const float* w_hh  = (const float*)d_in[3];
    const float* b_ih  = (const float*)d_in[4];
    const float* b_hh  = (const float*)d_in[5];
    const float* w_lin = (const float*)d_in[6];
    const float* b_lin = (const float*)d_in[7];
    const float* w_fc  = (const float*)d_in[8];
    const float* b_fc  = (const float*)d_in[9];
    float* out = (float*)d_out;

    lstm_pk_kernel<<<dim3(BATCH / 2), dim3(64), 0, stream>>>(
        x, w_ih0, w_ih, w_hh, b_ih, b_hh, w_lin, b_lin, w_fc, b_fc, out);
}